// Round 2
// baseline (520.073 us; speedup 1.0000x reference)
//
#include <hip/hip_runtime.h>
#include <hip/hip_bf16.h>

#define S_LEN 2048
#define DMODEL 1024
#define NHEAD 16
#define DHEAD 64
#define BATCH 4
#define MTOT (BATCH * S_LEN)   // 8192 rows

typedef __attribute__((ext_vector_type(8))) short short8;
typedef __attribute__((ext_vector_type(8))) unsigned short ushort8;
typedef __attribute__((ext_vector_type(4))) unsigned short ushort4v;
typedef __attribute__((ext_vector_type(4))) float f32x4;

__device__ __forceinline__ unsigned short f2bf(float x) {
    unsigned int u = __float_as_uint(x);
    u += 0x7FFFu + ((u >> 16) & 1u);   // RNE
    return (unsigned short)(u >> 16);
}

// ---------------- fp32 -> bf16 convert, 3 tensors in one launch ----------------
__global__ __launch_bounds__(256) void k_conv3(const float* __restrict__ s0, const float* __restrict__ s1,
                                               const float* __restrict__ s2,
                                               unsigned short* __restrict__ d0, unsigned short* __restrict__ d1,
                                               unsigned short* __restrict__ d2, int n8) {
    int i = blockIdx.x * 256 + threadIdx.x;
    if (i >= n8) return;
    const float* src = blockIdx.y == 0 ? s0 : (blockIdx.y == 1 ? s1 : s2);
    unsigned short* dst = blockIdx.y == 0 ? d0 : (blockIdx.y == 1 ? d1 : d2);
    const float4* s4 = (const float4*)src;
    float4 a = s4[(size_t)i * 2];
    float4 b = s4[(size_t)i * 2 + 1];
    ushort8 v;
    v[0] = f2bf(a.x); v[1] = f2bf(a.y); v[2] = f2bf(a.z); v[3] = f2bf(a.w);
    v[4] = f2bf(b.x); v[5] = f2bf(b.y); v[6] = f2bf(b.z); v[7] = f2bf(b.w);
    *(ushort8*)(dst + (size_t)i * 8) = v;
}

// ---------------- weight transpose-convert: W[k][n] f32 -> Wt[n][k] bf16 ----------------
__global__ __launch_bounds__(256) void k_transpose_w(const float* __restrict__ W0, const float* __restrict__ W1,
                                                     const float* __restrict__ W2, const float* __restrict__ W3,
                                                     unsigned short* __restrict__ T0, unsigned short* __restrict__ T1,
                                                     unsigned short* __restrict__ T2, unsigned short* __restrict__ T3) {
    const float* src; unsigned short* dst;
    switch (blockIdx.z) {
        case 0: src = W0; dst = T0; break;
        case 1: src = W1; dst = T1; break;
        case 2: src = W2; dst = T2; break;
        default: src = W3; dst = T3; break;
    }
    __shared__ float t[32][33];
    int tx = threadIdx.x & 31, ty = threadIdx.x >> 5;  // 32 x 8
    int n0 = blockIdx.x * 32, k0 = blockIdx.y * 32;
#pragma unroll
    for (int i = 0; i < 32; i += 8)
        t[ty + i][tx] = src[(size_t)(k0 + ty + i) * DMODEL + n0 + tx];
    __syncthreads();
#pragma unroll
    for (int i = 0; i < 32; i += 8)
        dst[(size_t)(n0 + ty + i) * DMODEL + k0 + tx] = f2bf(t[tx][ty + i]);
}

// ================= fused QKV projection GEMM =================
// C = A * Bt^T + bias ; z selects (A,Bt,bias,dst). z==2 writes V transposed per head:
// Vt[(b*16+h)*64 + d][s].  128x128 tile, BK=32, XCD-chunked tile swizzle.
__global__ __launch_bounds__(256) void k_gemm_qkv(const unsigned short* __restrict__ Xq,
                                                  const unsigned short* __restrict__ Xk,
                                                  const unsigned short* __restrict__ Xv,
                                                  const unsigned short* __restrict__ Tq,
                                                  const unsigned short* __restrict__ Tk,
                                                  const unsigned short* __restrict__ Tv,
                                                  const float* __restrict__ bqp, const float* __restrict__ bkp,
                                                  const float* __restrict__ bvp,
                                                  unsigned short* __restrict__ Qp, unsigned short* __restrict__ Kp,
                                                  unsigned short* __restrict__ Vt) {
    int z = blockIdx.z;
    const unsigned short* A = z == 0 ? Xq : (z == 1 ? Xk : Xv);
    const unsigned short* Bt = z == 0 ? Tq : (z == 1 ? Tk : Tv);
    const float* bias = z == 0 ? bqp : (z == 1 ? bkp : bvp);
    float alpha = z == 0 ? 0.125f : 1.0f;   // fold 1/sqrt(DH) into Q

    __shared__ unsigned short Al[128 * 32];
    __shared__ unsigned short Bl[128 * 32];
    int tid = threadIdx.x;
    int wid = tid >> 6, lane = tid & 63;
    int lr = lane & 15, lg = lane >> 4;
    // XCD-chunked swizzle: nwg=512 per z-slice, 64 tiles per XCD (8 tile_m rows x all 8 tile_n)
    int lin = blockIdx.y * 8 + blockIdx.x;
    int tile = (lin & 7) * 64 + (lin >> 3);
    int bm = (tile >> 3) * 128, bn = (tile & 7) * 128;
    int wm = (wid >> 1) * 64, wn = (wid & 1) * 64;

    f32x4 acc[4][4];
#pragma unroll
    for (int mt = 0; mt < 4; ++mt)
#pragma unroll
        for (int nt = 0; nt < 4; ++nt) acc[mt][nt] = (f32x4)0.0f;

    for (int k0 = 0; k0 < DMODEL; k0 += 32) {
#pragma unroll
        for (int i = 0; i < 2; ++i) {
            int c = (wid * 2 + i) * 64 + lane;
            int row = c >> 2, cc = c & 3;
            const unsigned short* ga = A + (size_t)(bm + row) * DMODEL + k0 + cc * 8;
            const unsigned short* gb = Bt + (size_t)(bn + row) * DMODEL + k0 + cc * 8;
            __builtin_amdgcn_global_load_lds((const __attribute__((address_space(1))) unsigned int*)ga,
                                             (__attribute__((address_space(3))) unsigned int*)(Al + (wid * 2 + i) * 512),
                                             16, 0, 0);
            __builtin_amdgcn_global_load_lds((const __attribute__((address_space(1))) unsigned int*)gb,
                                             (__attribute__((address_space(3))) unsigned int*)(Bl + (wid * 2 + i) * 512),
                                             16, 0, 0);
        }
        __syncthreads();
        short8 af[4], bf[4];
#pragma unroll
        for (int mt = 0; mt < 4; ++mt)
            af[mt] = *(const short8*)(Al + (wm + mt * 16 + lr) * 32 + lg * 8);
#pragma unroll
        for (int nt = 0; nt < 4; ++nt)
            bf[nt] = *(const short8*)(Bl + (wn + nt * 16 + lr) * 32 + lg * 8);
        __builtin_amdgcn_s_setprio(1);
#pragma unroll
        for (int mt = 0; mt < 4; ++mt)
#pragma unroll
            for (int nt = 0; nt < 4; ++nt)
                acc[mt][nt] = __builtin_amdgcn_mfma_f32_16x16x32_bf16(af[mt], bf[nt], acc[mt][nt], 0, 0, 0);
        __builtin_amdgcn_s_setprio(0);
        __syncthreads();
    }

#pragma unroll
    for (int nt = 0; nt < 4; ++nt) {
        int col = bn + wn + nt * 16 + lr;
        float bv = bias[col];
#pragma unroll
        for (int mt = 0; mt < 4; ++mt) {
#pragma unroll
            for (int r = 0; r < 4; ++r) {
                int row = bm + wm + mt * 16 + lg * 4 + r;
                float v = (acc[mt][nt][r] + bv) * alpha;
                if (z < 2) {
                    unsigned short* dst = z == 0 ? Qp : Kp;
                    dst[(size_t)row * DMODEL + col] = f2bf(v);
                } else {
                    int h = col >> 6, d = col & 63;
                    int b = row >> 11, s = row & 2047;
                    Vt[((size_t)(b * NHEAD + h) * DHEAD + d) * S_LEN + s] = f2bf(v);
                }
            }
        }
    }
}

// ---------------- output projection GEMM (fp32 out) ----------------
__global__ __launch_bounds__(256) void k_gemm_out(const unsigned short* __restrict__ A,
                                                  const unsigned short* __restrict__ Bt,
                                                  const float* __restrict__ bias,
                                                  float* __restrict__ Cout) {
    __shared__ unsigned short Al[128 * 32];
    __shared__ unsigned short Bl[128 * 32];
    int tid = threadIdx.x;
    int wid = tid >> 6, lane = tid & 63;
    int lr = lane & 15, lg = lane >> 4;
    int lin = blockIdx.y * 8 + blockIdx.x;
    int tile = (lin & 7) * 64 + (lin >> 3);
    int bm = (tile >> 3) * 128, bn = (tile & 7) * 128;
    int wm = (wid >> 1) * 64, wn = (wid & 1) * 64;

    f32x4 acc[4][4];
#pragma unroll
    for (int mt = 0; mt < 4; ++mt)
#pragma unroll
        for (int nt = 0; nt < 4; ++nt) acc[mt][nt] = (f32x4)0.0f;

    for (int k0 = 0; k0 < DMODEL; k0 += 32) {
#pragma unroll
        for (int i = 0; i < 2; ++i) {
            int c = (wid * 2 + i) * 64 + lane;
            int row = c >> 2, cc = c & 3;
            const unsigned short* ga = A + (size_t)(bm + row) * DMODEL + k0 + cc * 8;
            const unsigned short* gb = Bt + (size_t)(bn + row) * DMODEL + k0 + cc * 8;
            __builtin_amdgcn_global_load_lds((const __attribute__((address_space(1))) unsigned int*)ga,
                                             (__attribute__((address_space(3))) unsigned int*)(Al + (wid * 2 + i) * 512),
                                             16, 0, 0);
            __builtin_amdgcn_global_load_lds((const __attribute__((address_space(1))) unsigned int*)gb,
                                             (__attribute__((address_space(3))) unsigned int*)(Bl + (wid * 2 + i) * 512),
                                             16, 0, 0);
        }
        __syncthreads();
        short8 af[4], bf[4];
#pragma unroll
        for (int mt = 0; mt < 4; ++mt)
            af[mt] = *(const short8*)(Al + (wm + mt * 16 + lr) * 32 + lg * 8);
#pragma unroll
        for (int nt = 0; nt < 4; ++nt)
            bf[nt] = *(const short8*)(Bl + (wn + nt * 16 + lr) * 32 + lg * 8);
        __builtin_amdgcn_s_setprio(1);
#pragma unroll
        for (int mt = 0; mt < 4; ++mt)
#pragma unroll
            for (int nt = 0; nt < 4; ++nt)
                acc[mt][nt] = __builtin_amdgcn_mfma_f32_16x16x32_bf16(af[mt], bf[nt], acc[mt][nt], 0, 0, 0);
        __builtin_amdgcn_s_setprio(0);
        __syncthreads();
    }

#pragma unroll
    for (int nt = 0; nt < 4; ++nt) {
        int col = bn + wn + nt * 16 + lr;
        float bv = bias[col];
#pragma unroll
        for (int mt = 0; mt < 4; ++mt)
#pragma unroll
            for (int r = 0; r < 4; ++r) {
                int row = bm + wm + mt * 16 + lg * 4 + r;
                Cout[(size_t)row * DMODEL + col] = acc[mt][nt][r] + bv;
            }
    }
}

// ================= causal flash attention =================
// One wave per 64-row Q block. S^T = mfma(K,Q); PV: ctx^T = mfma(V^T, P^T) with a shared
// k-slot bijection kk = 32ks + 16(j>>2) + 4lg + (j&3) so P^T feeds B directly from registers
// and V^T fragments are two 8B vector loads each from the per-head Vt[d][s] layout.
// Block remap: each XCD owns 8 heads (K+Vt ~4MB = its L2), biggest qb dispatched first.
__global__ __launch_bounds__(64, 3) void k_attn(const unsigned short* __restrict__ Qp,
                                                const unsigned short* __restrict__ Kp,
                                                const unsigned short* __restrict__ Vt,
                                                unsigned short* __restrict__ Ctx) {
    int lane = threadIdx.x & 63;
    int lr = lane & 15, lg = lane >> 4;
    int bid = blockIdx.x;                 // 0..2047
    int xcd = bid & 7;
    int j = bid >> 3;                     // 0..255
    int bh = xcd + 8 * (j & 7);           // 8 heads per XCD
    int qb = (S_LEN / 64 - 1) - (j >> 3); // biggest q-block first
    int b = bh >> 4, h = bh & 15;
    size_t baserow = (size_t)b * S_LEN;
    int hcol = h * DHEAD;

    short8 qf[4][2];
#pragma unroll
    for (int qt = 0; qt < 4; ++qt)
#pragma unroll
        for (int ks = 0; ks < 2; ++ks)
            qf[qt][ks] = *(const short8*)(Qp + (baserow + qb * 64 + qt * 16 + lr) * DMODEL + hcol + ks * 32 + lg * 8);

    f32x4 ctx[4][4];   // [dt][qt]
#pragma unroll
    for (int dt = 0; dt < 4; ++dt)
#pragma unroll
        for (int qt = 0; qt < 4; ++qt) ctx[dt][qt] = (f32x4)0.0f;

    float mrun[4], lrun[4];
#pragma unroll
    for (int qt = 0; qt < 4; ++qt) { mrun[qt] = -1e30f; lrun[qt] = 0.0f; }

    const unsigned short* vth = Vt + (size_t)bh * DHEAD * S_LEN;

    for (int kb = 0; kb <= qb; ++kb) {
        // ---- S^T = K * Q^T ----
        f32x4 s[4][4];
#pragma unroll
        for (int kt = 0; kt < 4; ++kt)
#pragma unroll
            for (int qt = 0; qt < 4; ++qt) s[kt][qt] = (f32x4)0.0f;
#pragma unroll
        for (int kt = 0; kt < 4; ++kt) {
            short8 kf[2];
#pragma unroll
            for (int ks = 0; ks < 2; ++ks)
                kf[ks] = *(const short8*)(Kp + (baserow + kb * 64 + kt * 16 + lr) * DMODEL + hcol + ks * 32 + lg * 8);
            __builtin_amdgcn_s_setprio(1);
#pragma unroll
            for (int qt = 0; qt < 4; ++qt)
#pragma unroll
                for (int ks = 0; ks < 2; ++ks)
                    s[kt][qt] = __builtin_amdgcn_mfma_f32_16x16x32_bf16(kf[ks], qf[qt][ks], s[kt][qt], 0, 0, 0);
            __builtin_amdgcn_s_setprio(0);
        }

        // ---- prefetch V^T fragments (overlaps softmax VALU) ----
        short8 vf[4][2];
        {
            const unsigned short* vb = vth + (size_t)kb * 64 + 4 * lg;
#pragma unroll
            for (int dt = 0; dt < 4; ++dt)
#pragma unroll
                for (int ks = 0; ks < 2; ++ks) {
                    ushort4v lo = *(const ushort4v*)(vb + (size_t)(dt * 16 + lr) * S_LEN + 32 * ks);
                    ushort4v hi = *(const ushort4v*)(vb + (size_t)(dt * 16 + lr) * S_LEN + 32 * ks + 16);
                    short8 t;
                    t[0] = (short)lo[0]; t[1] = (short)lo[1]; t[2] = (short)lo[2]; t[3] = (short)lo[3];
                    t[4] = (short)hi[0]; t[5] = (short)hi[1]; t[6] = (short)hi[2]; t[7] = (short)hi[3];
                    vf[dt][ks] = t;
                }
        }

        if (kb == qb) {   // causal mask inside diagonal block
#pragma unroll
            for (int kt = 0; kt < 4; ++kt)
#pragma unroll
                for (int qt = 0; qt < 4; ++qt)
#pragma unroll
                    for (int r = 0; r < 4; ++r)
                        if (kt * 16 + lg * 4 + r > qt * 16 + lr) s[kt][qt][r] = -1e30f;
        }

        // ---- online softmax per q column; build P^T fragments ----
        short8 pf[4][2];
#pragma unroll
        for (int qt = 0; qt < 4; ++qt) {
            float mx = -1e30f;
#pragma unroll
            for (int kt = 0; kt < 4; ++kt)
#pragma unroll
                for (int r = 0; r < 4; ++r) mx = fmaxf(mx, s[kt][qt][r]);
            mx = fmaxf(mx, __shfl_xor(mx, 16));
            mx = fmaxf(mx, __shfl_xor(mx, 32));
            float mnew = fmaxf(mrun[qt], mx);
            float scale = __expf(mrun[qt] - mnew);
            mrun[qt] = mnew;
            float rs = 0.0f;
#pragma unroll
            for (int kt = 0; kt < 4; ++kt)
#pragma unroll
                for (int r = 0; r < 4; ++r) {
                    float p = __expf(s[kt][qt][r] - mnew);
                    s[kt][qt][r] = p;
                    rs += p;
                }
            rs += __shfl_xor(rs, 16);
            rs += __shfl_xor(rs, 32);
            lrun[qt] = lrun[qt] * scale + rs;
#pragma unroll
            for (int dt = 0; dt < 4; ++dt)
#pragma unroll
                for (int r = 0; r < 4; ++r) ctx[dt][qt][r] *= scale;
#pragma unroll
            for (int ks = 0; ks < 2; ++ks)
#pragma unroll
                for (int jj = 0; jj < 8; ++jj)
                    pf[qt][ks][jj] = (short)f2bf(s[2 * ks + (jj >> 2)][qt][jj & 3]);
        }

        // ---- ctx^T += V^T * P^T ----
        __builtin_amdgcn_s_setprio(1);
#pragma unroll
        for (int dt = 0; dt < 4; ++dt)
#pragma unroll
            for (int ks = 0; ks < 2; ++ks)
#pragma unroll
                for (int qt = 0; qt < 4; ++qt)
                    ctx[dt][qt] = __builtin_amdgcn_mfma_f32_16x16x32_bf16(vf[dt][ks], pf[qt][ks], ctx[dt][qt], 0, 0, 0);
        __builtin_amdgcn_s_setprio(0);
    }

    // ---- normalize and store ----
#pragma unroll
    for (int qt = 0; qt < 4; ++qt) {
        float inv = 1.0f / lrun[qt];
#pragma unroll
        for (int dt = 0; dt < 4; ++dt) {
            unsigned int lo = (unsigned int)f2bf(ctx[dt][qt][0] * inv) | ((unsigned int)f2bf(ctx[dt][qt][1] * inv) << 16);
            unsigned int hi = (unsigned int)f2bf(ctx[dt][qt][2] * inv) | ((unsigned int)f2bf(ctx[dt][qt][3] * inv) << 16);
            uint2 vv; vv.x = lo; vv.y = hi;
            *(uint2*)(Ctx + (baserow + qb * 64 + qt * 16 + lr) * DMODEL + hcol + dt * 16 + lg * 4) = vv;
        }
    }
}

// ---------------- host launch ----------------
extern "C" void kernel_launch(void* const* d_in, const int* in_sizes, int n_in,
                              void* d_out, int out_size, void* d_ws, size_t ws_size,
                              hipStream_t stream) {
    const float* q_in = (const float*)d_in[0];
    const float* k_in = (const float*)d_in[1];
    const float* v_in = (const float*)d_in[2];
    const float* Wq = (const float*)d_in[4];
    const float* bq = (const float*)d_in[5];
    const float* Wk = (const float*)d_in[6];
    const float* bk = (const float*)d_in[7];
    const float* Wv = (const float*)d_in[8];
    const float* bv = (const float*)d_in[9];
    const float* Wo = (const float*)d_in[10];
    const float* bo = (const float*)d_in[11];

    char* ws = (char*)d_ws;
    const size_t SZ_ACT = (size_t)MTOT * DMODEL * 2;
    const size_t SZ_W = (size_t)DMODEL * DMODEL * 2;
    unsigned short* Xq = (unsigned short*)(ws);
    unsigned short* Xk = (unsigned short*)(ws + SZ_ACT);
    unsigned short* Xv = (unsigned short*)(ws + 2 * SZ_ACT);
    unsigned short* Tq = (unsigned short*)(ws + 3 * SZ_ACT);
    unsigned short* Tk = (unsigned short*)(ws + 3 * SZ_ACT + SZ_W);
    unsigned short* Tv = (unsigned short*)(ws + 3 * SZ_ACT + 2 * SZ_W);
    unsigned short* To = (unsigned short*)(ws + 3 * SZ_ACT + 3 * SZ_W);
    unsigned short* Qp = (unsigned short*)(ws + 3 * SZ_ACT + 4 * SZ_W);
    unsigned short* Kp = (unsigned short*)(ws + 4 * SZ_ACT + 4 * SZ_W);
    unsigned short* Vt = (unsigned short*)(ws + 5 * SZ_ACT + 4 * SZ_W);
    unsigned short* Cx = (unsigned short*)(ws + 6 * SZ_ACT + 4 * SZ_W);

    int n8 = MTOT * DMODEL / 8;
    k_conv3<<<dim3((n8 + 255) / 256, 3), 256, 0, stream>>>(q_in, k_in, v_in, Xq, Xk, Xv, n8);
    k_transpose_w<<<dim3(32, 32, 4), 256, 0, stream>>>(Wq, Wk, Wv, Wo, Tq, Tk, Tv, To);

    k_gemm_qkv<<<dim3(8, 64, 3), 256, 0, stream>>>(Xq, Xk, Xv, Tq, Tk, Tv, bq, bk, bv, Qp, Kp, Vt);

    k_attn<<<dim3((S_LEN / 64) * BATCH * NHEAD), 64, 0, stream>>>(Qp, Kp, Vt, Cx);

    k_gemm_out<<<dim3(8, 64), 256, 0, stream>>>(Cx, To, bo, (float*)d_out);
}